// Round 1
// 1744.174 us; speedup vs baseline: 1.1735x; 1.1735x over previous
//
#include <hip/hip_runtime.h>
#include <cstdint>
#include <cfloat>
#include <climits>

#define NPTS 20000
#define NB 4
#define MP 1024
#define CF 512
#define MAXCH 20         // compaction chunks (20*1024 >= 20000)
#define PFIX 10          // fallback-era constant (kept for K coverage math)
#define KFAST 10240      // fast path covers K <= 10240 (K~9000 expected)
#define NWORK 8          // working waves in FPS loop (512 threads)
#define PPT 20           // points per working thread: 512*20 = 10240 = KFAST

__constant__ float c_r2[4]  = { (float)(0.025*0.025), (float)(0.05*0.05),
                                (float)(0.075*0.075), (float)(0.1*0.1) };
__constant__ float c_rad[4] = { 0.025f, 0.05f, 0.075f, 0.1f };

// DPP ctrl codes (gfx9/CDNA encoding)
#define DPP_XOR1   0xB1   // quad_perm {1,0,3,2}
#define DPP_XOR2   0x4E   // quad_perm {2,3,0,1}
#define DPP_HMIRR  0x141  // row_half_mirror = xor7 within 8
#define DPP_MIRR   0x140  // row_mirror = xor15 within 16
#define DPP_BC15   0x142  // broadcast lane15 of each row to next row
#define DPP_BC31   0x143  // broadcast lane31 to lanes 32..63

// One DPP butterfly/broadcast step of a 64-bit max-reduce, entirely on VALU.
// bound_ctrl=false + old=src: lanes with no valid source keep their value,
// which is harmless under max.
template<int CTRL>
__device__ __forceinline__ unsigned long long kmax_step(unsigned long long k)
{
    unsigned int lo = (unsigned int)k;
    unsigned int hi = (unsigned int)(k >> 32);
    unsigned int olo = (unsigned int)__builtin_amdgcn_update_dpp((int)lo, (int)lo, CTRL, 0xf, 0xf, false);
    unsigned int ohi = (unsigned int)__builtin_amdgcn_update_dpp((int)hi, (int)hi, CTRL, 0xf, 0xf, false);
    unsigned long long ok = ((unsigned long long)ohi << 32) | (unsigned long long)olo;
    return (ok > k) ? ok : k;
}

// ---------------------------------------------------------------------------
// K1: masked FPS over the compacted masked point set, one block per batch.
// Fast path: 8 working waves x 20 points in REGISTERS (constant-index full
// unroll -> SROA); waves 8..15 only service the barrier. Argmax reduction is
// a pure-VALU DPP butterfly (no ds_bpermute): intra-wave 6 DPP steps put the
// wave max in lane 63; cross-wave is one b64 broadcast read + 3 DPP steps.
// Exact numerics: rn ops, no FMA contraction; tie-break = min index.
// ---------------------------------------------------------------------------
__global__ __launch_bounds__(1024, 4)
void k_fps(const float* __restrict__ xyz, const float* __restrict__ obj,
           const float* __restrict__ grasp, int* __restrict__ idxs,
           float* __restrict__ xyz_g,
           float* __restrict__ xc, float* __restrict__ yc,
           float* __restrict__ zc, int* __restrict__ ci)
{
    const int b = blockIdx.x;
    const int tid = threadIdx.x;
    const int lane = tid & 63, wid = tid >> 6;
    const float* xb  = xyz   + (size_t)b * NPTS * 3;
    const float* ob0 = obj   + (size_t)b * 2 * NPTS;
    const float* ob1 = ob0 + NPTS;
    const float* gb  = grasp + (size_t)b * NPTS;
    float* xcb = xc + (size_t)b * 20480;
    float* ycb = yc + (size_t)b * 20480;
    float* zcb = zc + (size_t)b * 20480;
    int*   cib = ci + (size_t)b * 20480;

    __shared__ float sXYZ[3 * KFAST];          // 120 KB: x | y | z mirrors
    __shared__ int   s_sel[MP];                // 4 KB
    __shared__ unsigned long long sKey[2][16];
    __shared__ int   sWaveCnt[16];
    float* sX = sXYZ;
    float* sY = sXYZ + KFAST;
    float* sZ = sXYZ + 2 * KFAST;

    // ---- phase A: order-preserving compaction of masked points ----
    int kbase = 0;
    for (int i = 0; i < MAXCH; ++i) {
        int n = i * MP + tid;
        bool msk = false; float x = 0.f, y = 0.f, z = 0.f;
        if (n < NPTS) {
            msk = (ob1[n] > ob0[n]) && (gb[n] > 0.1f);
            if (msk) { x = xb[n*3+0]; y = xb[n*3+1]; z = xb[n*3+2]; }
        }
        unsigned long long bal = __ballot(msk);
        if (lane == 0) sWaveCnt[wid] = __popcll(bal);
        __syncthreads();
        int pre = 0, tot = 0;
        for (int w = 0; w < 16; ++w) { int c = sWaveCnt[w]; tot += c; if (w < wid) pre += c; }
        if (msk) {
            int rank = kbase + pre + __popcll(bal & ((1ull << lane) - 1ull));
            xcb[rank] = x; ycb[rank] = y; zcb[rank] = z; cib[rank] = n;
            if (rank < KFAST) { sX[rank] = x; sY[rank] = y; sZ[rank] = z; }
        }
        kbase += tot;
        __syncthreads();
    }
    const int K = kbase;                 // uniform across block

    if (K == 0) {                        // ref: argmax of all-equal -> 0 forever
        idxs[b*MP + tid] = 0;
        xyz_g[((size_t)b*MP + tid)*3 + 0] = xb[0];
        xyz_g[((size_t)b*MP + tid)*3 + 1] = xb[1];
        xyz_g[((size_t)b*MP + tid)*3 + 2] = xb[2];
        return;
    }

    if (K <= KFAST) {
        // ========== FAST PATH: 8 waves x 20 pts, DPP argmax reduce ==========
        const bool work = (wid < NWORK);         // wave-uniform
        float px[PPT], py[PPT], pz[PPT], pd[PPT];
        if (work) {
#pragma unroll
            for (int i = 0; i < PPT; ++i) {
                int c = tid + (i << 9);          // c = tid + i*512, tid < 512
                bool v = c < K;
                px[i] = v ? sX[c] : 0.f;
                py[i] = v ? sY[c] : 0.f;
                pz[i] = v ? sZ[c] : 0.f;
                pd[i] = v ? 1e10f : -3.0e38f;
            }
        }
        float lx = sX[0], ly = sY[0], lz = sZ[0];
        if (tid == 0) s_sel[0] = 0;

        for (int it = 1; it < MP; ++it) {
            const int p = it & 1;
            if (work) {
                float bv = -3.4e38f; int bn = 0;
#pragma unroll
                for (int i = 0; i < PPT; ++i) {
                    float dx = px[i] - lx, dy = py[i] - ly, dz = pz[i] - lz;
                    float d = __fadd_rn(__fadd_rn(__fmul_rn(dx,dx), __fmul_rn(dy,dy)),
                                        __fmul_rn(dz,dz));
                    float nd = fminf(pd[i], d);
                    pd[i] = nd;
                    bool w = nd > bv;
                    bn = w ? (tid + (i << 9)) : bn;
                    bv = fmaxf(bv, nd);
                }
                unsigned int ob = __float_as_uint(bv);
                unsigned int ord = (ob & 0x80000000u) ? ~ob : (ob | 0x80000000u);
                unsigned long long key = ((unsigned long long)ord << 32)
                                       | (unsigned int)(~bn);
                // intra-wave 64-lane max: xor1,xor2,xor7,xor15 (full 16-group),
                // then bcast15+bcast31 accumulate the 4 groups into lane 63
                key = kmax_step<DPP_XOR1 >(key);
                key = kmax_step<DPP_XOR2 >(key);
                key = kmax_step<DPP_HMIRR>(key);
                key = kmax_step<DPP_MIRR >(key);
                key = kmax_step<DPP_BC15 >(key);
                key = kmax_step<DPP_BC31 >(key);
                if (lane == 63) sKey[p][wid] = key;
            }
            __syncthreads();
            if (work) {
                // every lane reads one of the 8 wave keys (b64 broadcast),
                // 3 DPP steps give the global max in ALL lanes
                unsigned long long k2 = sKey[p][lane & 7];
                k2 = kmax_step<DPP_XOR1 >(k2);
                k2 = kmax_step<DPP_XOR2 >(k2);
                k2 = kmax_step<DPP_HMIRR>(k2);
                int n = ~((unsigned int)k2);
                lx = sX[n]; ly = sY[n]; lz = sZ[n];   // LDS broadcast
                if (tid == 0) s_sel[it] = n;
            }
        }
        __syncthreads();
        int nc = s_sel[tid];
        idxs[b*MP + tid] = cib[nc];
        xyz_g[((size_t)b*MP + tid)*3 + 0] = sX[nc];
        xyz_g[((size_t)b*MP + tid)*3 + 1] = sY[nc];
        xyz_g[((size_t)b*MP + tid)*3 + 2] = sZ[nc];
        return;
    }

    // ================= FALLBACK (K > 10240): global reads, LDS dist ========
    {
        float* fD = sXYZ;                 // 30720 floats >= 20000
        for (int c = tid; c < K; c += MP) fD[c] = 1e10f;
        float lx = xcb[0], ly = ycb[0], lz = zcb[0];
        if (tid == 0) s_sel[0] = 0;
        __syncthreads();
        for (int it = 1; it < MP; ++it) {
            float bv = -3.4e38f; int bn = 0;
            for (int c = tid; c < K; c += MP) {
                float dx = xcb[c] - lx, dy = ycb[c] - ly, dz = zcb[c] - lz;
                float d = __fadd_rn(__fadd_rn(__fmul_rn(dx,dx), __fmul_rn(dy,dy)),
                                    __fmul_rn(dz,dz));
                float nd = fminf(fD[c], d);
                fD[c] = nd;
                bool w = nd > bv;
                bn = w ? c : bn;
                bv = fmaxf(bv, nd);
            }
            unsigned int ob = __float_as_uint(bv);
            unsigned int ord = (ob & 0x80000000u) ? ~ob : (ob | 0x80000000u);
            unsigned long long key = ((unsigned long long)ord << 32)
                                   | (unsigned int)(~bn);
#pragma unroll
            for (int off = 1; off < 64; off <<= 1) {
                unsigned long long ok = __shfl_xor(key, off);
                key = (ok > key) ? ok : key;
            }
            int p = it & 1;
            if (lane == 0) sKey[p][wid] = key;
            __syncthreads();
            unsigned long long k2 = sKey[p][lane & 15];
#pragma unroll
            for (int off = 1; off < 16; off <<= 1) {
                unsigned long long ok = __shfl_xor(k2, off);
                k2 = (ok > k2) ? ok : k2;
            }
            int n = ~((unsigned int)k2);
            lx = xcb[n]; ly = ycb[n]; lz = zcb[n];
            if (tid == 0) s_sel[it] = n;
        }
        __syncthreads();
        int nc = s_sel[tid];
        idxs[b*MP + tid] = cib[nc];
        xyz_g[((size_t)b*MP + tid)*3 + 0] = xcb[nc];
        xyz_g[((size_t)b*MP + tid)*3 + 1] = ycb[nc];
        xyz_g[((size_t)b*MP + tid)*3 + 2] = zcb[nc];
    }
}

// ---------------------------------------------------------------------------
// K2: gather feat_g[b,m,c] = seed_features[b,c,idx[m]]
// ---------------------------------------------------------------------------
__global__ void k_gather_feat(const float* __restrict__ sf, const int* __restrict__ idxs,
                              float* __restrict__ feat_g)
{
    int bm = blockIdx.x;
    int b = bm >> 10;
    int n = idxs[bm];
    const float* src = sf + (size_t)b*CF*NPTS + n;
    float* dst = feat_g + (size_t)bm*CF;
    for (int c = threadIdx.x; c < CF; c += 256) dst[c] = src[(size_t)c * NPTS];
}

// ---------------------------------------------------------------------------
// K3b: small prep - transpose w2 -> w2t[k][c][o], extract w1 xyz cols
// ---------------------------------------------------------------------------
__global__ void k_prep(const float* __restrict__ w1, const float* __restrict__ w2,
                       float* __restrict__ w2t, float* __restrict__ w1x)
{
    int k = blockIdx.x, cb = blockIdx.y*32, ob = blockIdx.z*32;
    int tx = threadIdx.x & 31, ty = threadIdx.x >> 5;
    __shared__ float t[32][33];
    for (int r = ty; r < 32; r += 8)
        t[r][tx] = w2[((size_t)k*256 + ob + r)*256 + cb + tx];
    __syncthreads();
    for (int r = ty; r < 32; r += 8)
        w2t[((size_t)k*256 + cb + r)*256 + ob + tx] = t[tx][r];
    if (blockIdx.y == 0 && blockIdx.z == 0) {
        int o = threadIdx.x;
        for (int d = 0; d < 3; ++d)
            w1x[(k*3 + d)*256 + o] = w1[((size_t)k*256 + o)*515 + d];
    }
}

// ---------------------------------------------------------------------------
// K3: F1[k][b*1024+n][o] = feat_g[b,n,:] . w1[k][o][3:] + b1[k][o]
// ---------------------------------------------------------------------------
__global__ __launch_bounds__(256)
void k_f1(const float* __restrict__ feat_g, const float* __restrict__ w1,
          const float* __restrict__ b1, float* __restrict__ F1)
{
    const int rt = blockIdx.x * 64;
    const int ot = blockIdx.y * 64;
    const int k  = blockIdx.z;
    const int tid = threadIdx.x;
    __shared__ float As[16][68];
    __shared__ float Bs[16][68];
    const int lr = tid >> 2;
    const int lc = (tid & 3) * 4;
    const int tr = (tid & 15) * 4;
    const int tc = (tid >> 4) * 4;
    float acc[4][4] = {};
    for (int kk = 0; kk < CF; kk += 16) {
        const float* ap = feat_g + (size_t)(rt + lr)*CF + kk + lc;
        As[lc+0][lr] = ap[0]; As[lc+1][lr] = ap[1];
        As[lc+2][lr] = ap[2]; As[lc+3][lr] = ap[3];
        const float* bp = w1 + (size_t)(k*256 + ot + lr)*515 + 3 + kk + lc;
        Bs[lc+0][lr] = bp[0]; Bs[lc+1][lr] = bp[1];
        Bs[lc+2][lr] = bp[2]; Bs[lc+3][lr] = bp[3];
        __syncthreads();
#pragma unroll
        for (int cc = 0; cc < 16; ++cc) {
            float a0=As[cc][tr+0], a1=As[cc][tr+1], a2=As[cc][tr+2], a3=As[cc][tr+3];
            float q0=Bs[cc][tc+0], q1=Bs[cc][tc+1], q2=Bs[cc][tc+2], q3=Bs[cc][tc+3];
            acc[0][0]+=a0*q0; acc[0][1]+=a0*q1; acc[0][2]+=a0*q2; acc[0][3]+=a0*q3;
            acc[1][0]+=a1*q0; acc[1][1]+=a1*q1; acc[1][2]+=a1*q2; acc[1][3]+=a1*q3;
            acc[2][0]+=a2*q0; acc[2][1]+=a2*q1; acc[2][2]+=a2*q2; acc[2][3]+=a2*q3;
            acc[3][0]+=a3*q0; acc[3][1]+=a3*q1; acc[3][2]+=a3*q2; acc[3][3]+=a3*q3;
        }
        __syncthreads();
    }
#pragma unroll
    for (int i = 0; i < 4; ++i)
#pragma unroll
        for (int j = 0; j < 4; ++j)
            F1[((size_t)k*4096 + rt+tr+i)*256 + ot+tc+j] = acc[i][j] + b1[k*256 + ot+tc+j];
}

// ---------------------------------------------------------------------------
// K4: cylinder neighbor query, one block per (b,m), thread = candidate n
// ---------------------------------------------------------------------------
__global__ __launch_bounds__(1024)
void k_nbr(const float* __restrict__ xyz_g, const float* __restrict__ rot,
           int* __restrict__ sel, float* __restrict__ lxyz, int* __restrict__ cnt)
{
    const int bm = blockIdx.x;
    const int b = bm >> 10;
    const int tid = threadIdx.x;
    const int lane = tid & 63, wid = tid >> 6;
    __shared__ float sR[9], sC[3];
    __shared__ int   sSel[4][16];
    __shared__ float sL[4][16][3];
    __shared__ int   sW[16];
    __shared__ int   sCnt[4];
    __shared__ float sFb[3];
    if (tid < 9) sR[tid] = rot[(size_t)bm*9 + tid];
    if (tid < 3) sC[tid] = xyz_g[(size_t)bm*3 + tid];
    __syncthreads();
    float x = xyz_g[((size_t)b*MP + tid)*3 + 0];
    float y = xyz_g[((size_t)b*MP + tid)*3 + 1];
    float z = xyz_g[((size_t)b*MP + tid)*3 + 2];
    float dx = x - sC[0], dy = y - sC[1], dz = z - sC[2];
    float l0 = __fadd_rn(__fadd_rn(__fmul_rn(dx,sR[0]), __fmul_rn(dy,sR[3])), __fmul_rn(dz,sR[6]));
    float l1 = __fadd_rn(__fadd_rn(__fmul_rn(dx,sR[1]), __fmul_rn(dy,sR[4])), __fmul_rn(dz,sR[7]));
    float l2 = __fadd_rn(__fadd_rn(__fmul_rn(dx,sR[2]), __fmul_rn(dy,sR[5])), __fmul_rn(dz,sR[8]));
    float r2 = __fadd_rn(__fmul_rn(l1,l1), __fmul_rn(l2,l2));
    bool basec = (l0 > -0.02f) && (l0 < 0.04f);
    if (tid == 0) { sFb[0]=l0; sFb[1]=l1; sFb[2]=l2; }
    for (int k = 0; k < 4; ++k) {
        bool c = basec && (r2 < c_r2[k]);
        unsigned long long bal = __ballot(c);
        if (lane == 0) sW[wid] = __popcll(bal);
        __syncthreads();
        int pre = 0, tot = 0;
        for (int w = 0; w < 16; ++w) { int cw = sW[w]; tot += cw; if (w < wid) pre += cw; }
        int rank = pre + __popcll(bal & ((1ull << lane) - 1ull));
        if (c && rank < 16) {
            sSel[k][rank] = tid;
            sL[k][rank][0] = l0; sL[k][rank][1] = l1; sL[k][rank][2] = l2;
        }
        if (tid == 0) sCnt[k] = min(tot, 16);
        __syncthreads();
    }
    if (tid < 64) {
        int k = tid >> 4, j = tid & 15;
        int ck = sCnt[k];
        int src = (j < ck) ? j : 0;
        int v; float a0, a1, a2;
        if (ck > 0) { v = sSel[k][src]; a0=sL[k][src][0]; a1=sL[k][src][1]; a2=sL[k][src][2]; }
        else        { v = 0; a0=sFb[0]; a1=sFb[1]; a2=sFb[2]; }
        size_t off = ((size_t)bm*4 + k)*16 + j;
        sel[off] = v;
        lxyz[off*3+0]=a0; lxyz[off*3+1]=a1; lxyz[off*3+2]=a2;
        if (j == 0) cnt[bm*4 + k] = (ck > 0) ? ck : 1;
    }
}

// ---------------------------------------------------------------------------
// K5: per-task MLP (layer1 via F1 gather + xyz part, layer2 + relu + max)
// ---------------------------------------------------------------------------
__global__ __launch_bounds__(256)
void k_mlp(const float* __restrict__ F1, const float* __restrict__ w1x,
           const float* __restrict__ w2t, const float* __restrict__ b2,
           const int* __restrict__ sel, const float* __restrict__ lxyz,
           const int* __restrict__ cnt, float* __restrict__ cat)
{
    const int gid = blockIdx.x;       // 1024 groups * 4 k
    const int k = gid & 3;
    const int g0 = (gid >> 2) * 4;    // bm base (groups never straddle a batch)
    const int o = threadIdx.x;
    __shared__ float h1s[64][256];    // 64 KB
    int u0 = cnt[(g0+0)*4 + k], u1 = cnt[(g0+1)*4 + k],
        u2 = cnt[(g0+2)*4 + k], u3 = cnt[(g0+3)*4 + k];
    int off1 = u0, off2 = u0+u1, off3 = off2+u2, tot = off3+u3;
    const float wx0 = w1x[(k*3+0)*256 + o];
    const float wx1 = w1x[(k*3+1)*256 + o];
    const float wx2 = w1x[(k*3+2)*256 + o];
    const float rad = c_rad[k];
    const int bbase = (g0 >> 10) * MP;
    for (int r = 0; r < tot; ++r) {
        int t = (r >= off1) + (r >= off2) + (r >= off3);
        int toff = (t==0) ? 0 : ((t==1) ? off1 : ((t==2) ? off2 : off3));
        int j = r - toff;
        int bmk = (g0 + t)*4 + k;
        int n = sel[(size_t)bmk*16 + j];
        float lx = lxyz[((size_t)bmk*16 + j)*3 + 0];
        float ly = lxyz[((size_t)bmk*16 + j)*3 + 1];
        float lz = lxyz[((size_t)bmk*16 + j)*3 + 2];
        float v = F1[((size_t)k*4096 + bbase + n)*256 + o];
        v += (lx/rad)*wx0 + (ly/rad)*wx1 + (lz/rad)*wx2;
        h1s[r][o] = fmaxf(v, 0.f);
    }
    __syncthreads();
    const float b2v = b2[k*256 + o];
    float m0=0.f, m1=0.f, m2=0.f, m3=0.f;
    const float* w2c = w2t + (size_t)k*65536 + o;
    for (int base = 0; base < tot; base += 4) {
        int r0 = base;
        int r1 = min(base+1, tot-1);
        int r2 = min(base+2, tot-1);
        int r3 = min(base+3, tot-1);
        float a0=0.f, a1=0.f, a2=0.f, a3=0.f;
        for (int c = 0; c < 256; c += 4) {
            float wA = w2c[(c+0)*256], wB = w2c[(c+1)*256];
            float wC = w2c[(c+2)*256], wD = w2c[(c+3)*256];
            float4 h;
            h = *(const float4*)&h1s[r0][c]; a0 += h.x*wA + h.y*wB + h.z*wC + h.w*wD;
            h = *(const float4*)&h1s[r1][c]; a1 += h.x*wA + h.y*wB + h.z*wC + h.w*wD;
            h = *(const float4*)&h1s[r2][c]; a2 += h.x*wA + h.y*wB + h.z*wC + h.w*wD;
            h = *(const float4*)&h1s[r3][c]; a3 += h.x*wA + h.y*wB + h.z*wC + h.w*wD;
        }
#pragma unroll
        for (int q = 0; q < 4; ++q) {
            int r = base + q;
            if (r < tot) {
                float a = (q==0) ? a0 : ((q==1) ? a1 : ((q==2) ? a2 : a3));
                int t = (r >= off1) + (r >= off2) + (r >= off3);
                float val = fmaxf(a + b2v, 0.f);
                if      (t==0) m0 = fmaxf(m0, val);
                else if (t==1) m1 = fmaxf(m1, val);
                else if (t==2) m2 = fmaxf(m2, val);
                else           m3 = fmaxf(m3, val);
            }
        }
    }
    cat[(size_t)(g0+0)*1024 + k*256 + o] = m0;
    cat[(size_t)(g0+1)*1024 + k*256 + o] = m1;
    cat[(size_t)(g0+2)*1024 + k*256 + o] = m2;
    cat[(size_t)(g0+3)*1024 + k*256 + o] = m3;
}

// ---------------------------------------------------------------------------
// K6: transpose cat[b][m][f] -> catT[b][f][m]
// ---------------------------------------------------------------------------
__global__ void k_transpose(const float* __restrict__ cat, float* __restrict__ catT)
{
    int bt = blockIdx.x;
    int b = bt >> 10;
    int t2 = bt & 1023;
    int mi = (t2 >> 5) * 32, fi = (t2 & 31) * 32;
    int tx = threadIdx.x & 31, ty = threadIdx.x >> 5;
    __shared__ float t[32][33];
    const float* src = cat + (size_t)b * 1048576;
    float* dst = catT + (size_t)b * 1048576;
    for (int r = ty; r < 32; r += 8) t[r][tx] = src[(size_t)(mi + r)*1024 + fi + tx];
    __syncthreads();
    for (int r = ty; r < 32; r += 8) dst[(size_t)(fi + r)*1024 + mi + tx] = t[tx][r];
}

// ---------------------------------------------------------------------------
// K7: fused[b][o][m] = sum_f cat[b][m][f]*fuse_w[o][f] + fuse_b[o]
// ---------------------------------------------------------------------------
__global__ __launch_bounds__(256)
void k_fuse(const float* __restrict__ catT, const float* __restrict__ fw,
            const float* __restrict__ fb, float* __restrict__ out)
{
    const int o0 = blockIdx.x * 4;
    const int b = blockIdx.y;
    const int m = threadIdx.x * 4;
    const float* ct = catT + (size_t)b * 1048576 + m;
    float4 a0 = {0,0,0,0}, a1 = a0, a2 = a0, a3 = a0;
    for (int f = 0; f < 1024; ++f) {
        const float4 cv = *(const float4*)(ct + (size_t)f*1024);
        float w0 = fw[(size_t)(o0+0)*1024 + f];
        float w1 = fw[(size_t)(o0+1)*1024 + f];
        float w2 = fw[(size_t)(o0+2)*1024 + f];
        float w3 = fw[(size_t)(o0+3)*1024 + f];
        a0.x += cv.x*w0; a0.y += cv.y*w0; a0.z += cv.z*w0; a0.w += cv.w*w0;
        a1.x += cv.x*w1; a1.y += cv.y*w1; a1.z += cv.z*w1; a1.w += cv.w*w1;
        a2.x += cv.x*w2; a2.y += cv.y*w2; a2.z += cv.z*w2; a2.w += cv.w*w2;
        a3.x += cv.x*w3; a3.y += cv.y*w3; a3.z += cv.z*w3; a3.w += cv.w*w3;
    }
#pragma unroll
    for (int q = 0; q < 4; ++q) {
        float bb = fb[o0+q];
        float4 r = (q==0) ? a0 : ((q==1) ? a1 : ((q==2) ? a2 : a3));
        r.x += bb; r.y += bb; r.z += bb; r.w += bb;
        *(float4*)&out[((size_t)b*256 + o0 + q)*1024 + m] = r;
    }
}

// ---------------------------------------------------------------------------
extern "C" void kernel_launch(void* const* d_in, const int* in_sizes, int n_in,
                              void* d_out, int out_size, void* d_ws, size_t ws_size,
                              hipStream_t stream)
{
    const float* seed_xyz      = (const float*)d_in[0];
    const float* seed_features = (const float*)d_in[1];
    const float* objectness    = (const float*)d_in[2];
    const float* graspness     = (const float*)d_in[3];
    const float* rot           = (const float*)d_in[4];
    const float* w1            = (const float*)d_in[5];
    const float* b1            = (const float*)d_in[6];
    const float* w2            = (const float*)d_in[7];
    const float* b2            = (const float*)d_in[8];
    const float* fw            = (const float*)d_in[9];
    const float* fb            = (const float*)d_in[10];
    float* out = (float*)d_out;

    char* ws = (char*)d_ws;
    size_t off = 0;
    int*   idxs   = (int*)(ws + off);  off += 16u<<10;            // 16 KB
    float* xyz_g  = (float*)(ws + off); off += 48u<<10;           // 48 KB
    float* feat_g = (float*)(ws + off); off += 8u<<20;            // 8 MB
    float* F1     = (float*)(ws + off); off += 16u<<20;           // 16 MB
    float* w2t    = (float*)(ws + off); off += 1u<<20;            // 1 MB
    float* w1x    = (float*)(ws + off); off += 64u<<10;           // 12 KB used
    int*   sel    = (int*)(ws + off);   off += 1u<<20;            // 1 MB
    int*   cnt    = (int*)(ws + off);   off += 64u<<10;           // 64 KB
    float* lxyz   = (float*)(ws + off); off += 3u<<20;            // 3 MB
    float* cat    = (float*)(ws + off); off += 16u<<20;           // 16 MB
    float* catT   = (float*)(ws + off); off += 16u<<20;           // 16 MB

    // FPS compaction scratch aliases `cat` (first written much later by k_mlp)
    float* xc = cat;
    float* yc = cat + 4*20480;
    float* zc = cat + 8*20480;
    int*   ci = (int*)(cat + 12*20480);

    k_fps<<<NB, 1024, 0, stream>>>(seed_xyz, objectness, graspness, idxs, xyz_g,
                                   xc, yc, zc, ci);
    k_prep<<<dim3(4,8,8), 256, 0, stream>>>(w1, w2, w2t, w1x);
    k_gather_feat<<<NB*MP, 256, 0, stream>>>(seed_features, idxs, feat_g);
    k_f1<<<dim3(64,4,4), 256, 0, stream>>>(feat_g, w1, b1, F1);
    k_nbr<<<NB*MP, 1024, 0, stream>>>(xyz_g, rot, sel, lxyz, cnt);
    k_mlp<<<4096, 256, 0, stream>>>(F1, w1x, w2t, b2, sel, lxyz, cnt, cat);
    k_transpose<<<4096, 256, 0, stream>>>(cat, catT);
    k_fuse<<<dim3(64,4), 256, 0, stream>>>(catT, fw, fb, out);
}

// Round 3
// 1725.421 us; speedup vs baseline: 1.1863x; 1.0109x over previous
//
#include <hip/hip_runtime.h>
#include <cstdint>
#include <cfloat>
#include <climits>

#define NPTS 20000
#define NB 4
#define MP 1024
#define CF 512
#define MAXCH 20         // compaction chunks (20*1024 >= 20000)
#define KFAST 10240      // fast path covers K <= 10240 (K~9000 expected)
#define PPT 20           // points per thread in loop kernel: 512*20 = 10240

__constant__ float c_r2[4]  = { (float)(0.025*0.025), (float)(0.05*0.05),
                                (float)(0.075*0.075), (float)(0.1*0.1) };
__constant__ float c_rad[4] = { 0.025f, 0.05f, 0.075f, 0.1f };

// DPP ctrl codes (gfx9/CDNA encoding)
#define DPP_XOR1   0xB1   // quad_perm {1,0,3,2}
#define DPP_XOR2   0x4E   // quad_perm {2,3,0,1}
#define DPP_HMIRR  0x141  // row_half_mirror = xor7 within 8
#define DPP_MIRR   0x140  // row_mirror = xor15 within 16
#define DPP_BC15   0x142  // broadcast lane15 of each row to next row
#define DPP_BC31   0x143  // broadcast lane31 to lanes 32..63

// One DPP butterfly/broadcast step of a 64-bit max-reduce, entirely on VALU.
// bound_ctrl=false + old=src: lanes with no valid source keep their value,
// which is harmless under max.
template<int CTRL>
__device__ __forceinline__ unsigned long long kmax_step(unsigned long long k)
{
    unsigned int lo = (unsigned int)k;
    unsigned int hi = (unsigned int)(k >> 32);
    unsigned int olo = (unsigned int)__builtin_amdgcn_update_dpp((int)lo, (int)lo, CTRL, 0xf, 0xf, false);
    unsigned int ohi = (unsigned int)__builtin_amdgcn_update_dpp((int)hi, (int)hi, CTRL, 0xf, 0xf, false);
    unsigned long long ok = ((unsigned long long)ohi << 32) | (unsigned long long)olo;
    return (ok > k) ? ok : k;
}

// ---------------------------------------------------------------------------
// K1a: order-preserving compaction of masked points, one block per batch.
// Writes compacted x|y|z|orig-index arrays + K to global.
// ---------------------------------------------------------------------------
__global__ __launch_bounds__(1024)
void k_fps_compact(const float* __restrict__ xyz, const float* __restrict__ obj,
                   const float* __restrict__ grasp,
                   float* __restrict__ xc, float* __restrict__ yc,
                   float* __restrict__ zc, int* __restrict__ ci,
                   int* __restrict__ kv)
{
    const int b = blockIdx.x;
    const int tid = threadIdx.x;
    const int lane = tid & 63, wid = tid >> 6;
    const float* xb  = xyz   + (size_t)b * NPTS * 3;
    const float* ob0 = obj   + (size_t)b * 2 * NPTS;
    const float* ob1 = ob0 + NPTS;
    const float* gb  = grasp + (size_t)b * NPTS;
    float* xcb = xc + (size_t)b * 20480;
    float* ycb = yc + (size_t)b * 20480;
    float* zcb = zc + (size_t)b * 20480;
    int*   cib = ci + (size_t)b * 20480;

    __shared__ int sWaveCnt[16];

    int kbase = 0;
    for (int i = 0; i < MAXCH; ++i) {
        int n = i * MP + tid;
        bool msk = false; float x = 0.f, y = 0.f, z = 0.f;
        if (n < NPTS) {
            msk = (ob1[n] > ob0[n]) && (gb[n] > 0.1f);
            if (msk) { x = xb[n*3+0]; y = xb[n*3+1]; z = xb[n*3+2]; }
        }
        unsigned long long bal = __ballot(msk);
        if (lane == 0) sWaveCnt[wid] = __popcll(bal);
        __syncthreads();
        int pre = 0, tot = 0;
        for (int w = 0; w < 16; ++w) { int c = sWaveCnt[w]; tot += c; if (w < wid) pre += c; }
        if (msk) {
            int rank = kbase + pre + __popcll(bal & ((1ull << lane) - 1ull));
            xcb[rank] = x; ycb[rank] = y; zcb[rank] = z; cib[rank] = n;
        }
        kbase += tot;
        __syncthreads();
    }
    if (tid == 0) kv[b] = kbase;
}

// ---------------------------------------------------------------------------
// K1b: the serial FPS loop. 512 threads (8 waves), ALL working.
// launch_bounds(512,2) -> 256-VGPR cap: px/py/pz/pd[20] (80 regs) stay in
// true VGPRs (round-1's 1024-thread/128-cap variant spilled them -> AGPR
// shuffle, VGPR_Count=64). Argmax per thread is a 5-level cmp/cndmask TREE
// (not a 20-deep serial scan). Cross-lane: 6 DPP steps -> lane63, LDS,
// barrier, 3 DPP steps over 8 wave keys. Exact numerics preserved:
// rn ops, no contraction, first-max / min-index tie-break.
// ---------------------------------------------------------------------------
__global__ __launch_bounds__(512, 2)
void k_fps_loop(const float* __restrict__ xyz, const int* __restrict__ kv,
                const float* __restrict__ xc, const float* __restrict__ yc,
                const float* __restrict__ zc, const int* __restrict__ ci,
                int* __restrict__ idxs, float* __restrict__ xyz_g)
{
    const int b = blockIdx.x;
    const int tid = threadIdx.x;
    const int lane = tid & 63, wid = tid >> 6;   // 8 waves
    const float* xb  = xyz + (size_t)b * NPTS * 3;
    const float* xcb = xc + (size_t)b * 20480;
    const float* ycb = yc + (size_t)b * 20480;
    const float* zcb = zc + (size_t)b * 20480;
    const int*   cib = ci + (size_t)b * 20480;

    __shared__ float sXYZ[3 * KFAST];          // 120 KB: x | y | z mirrors
    __shared__ int   s_sel[MP];                // 4 KB
    __shared__ unsigned long long sKy[2][8];
    float* sX = sXYZ;
    float* sY = sXYZ + KFAST;
    float* sZ = sXYZ + 2 * KFAST;

    const int K = kv[b];

    if (K == 0) {                        // ref: argmax of all-equal -> 0 forever
        for (int t = tid; t < MP; t += 512) {
            idxs[b*MP + t] = 0;
            xyz_g[((size_t)b*MP + t)*3 + 0] = xb[0];
            xyz_g[((size_t)b*MP + t)*3 + 1] = xb[1];
            xyz_g[((size_t)b*MP + t)*3 + 2] = xb[2];
        }
        return;
    }

    if (K <= KFAST) {
        // ---- stage compacted coords into LDS (zero-padded to KFAST) ----
        for (int c = tid; c < KFAST; c += 512) {
            bool v = c < K;
            sX[c] = v ? xcb[c] : 0.f;
            sY[c] = v ? ycb[c] : 0.f;
            sZ[c] = v ? zcb[c] : 0.f;
        }
        __syncthreads();

        float px[PPT], py[PPT], pz[PPT], pd[PPT];
#pragma unroll
        for (int i = 0; i < PPT; ++i) {
            int c = tid + (i << 9);              // c = tid + i*512
            px[i] = sX[c]; py[i] = sY[c]; pz[i] = sZ[c];
            pd[i] = (c < K) ? 1e10f : -3.0e38f;
        }
        float lx = sX[0], ly = sY[0], lz = sZ[0];
        if (tid == 0) s_sel[0] = 0;

        for (int it = 1; it < MP; ++it) {
            const int p = it & 1;
            // ---- distance update (independent across the 20 points) ----
#pragma unroll
            for (int i = 0; i < PPT; ++i) {
                float dx = px[i] - lx, dy = py[i] - ly, dz = pz[i] - lz;
                float d = __fadd_rn(__fadd_rn(__fmul_rn(dx,dx), __fmul_rn(dy,dy)),
                                    __fmul_rn(dz,dz));
                pd[i] = fminf(pd[i], d);
            }
            // ---- per-thread argmax: tree, depth 5 (tie -> smaller i) ----
            float gv[5]; int gi[5];
#pragma unroll
            for (int g = 0; g < 5; ++g) {
                const int i0 = g * 4;
                bool t0 = pd[i0+1] > pd[i0+0];
                float v01 = t0 ? pd[i0+1] : pd[i0+0];
                int   i01 = t0 ? (i0+1) : (i0+0);
                bool t1 = pd[i0+3] > pd[i0+2];
                float v23 = t1 ? pd[i0+3] : pd[i0+2];
                int   i23 = t1 ? (i0+3) : (i0+2);
                bool t2 = v23 > v01;
                gv[g] = t2 ? v23 : v01;
                gi[g] = t2 ? i23 : i01;
            }
            bool tA = gv[1] > gv[0]; float vA = tA ? gv[1] : gv[0]; int iA = tA ? gi[1] : gi[0];
            bool tB = gv[3] > gv[2]; float vB = tB ? gv[3] : gv[2]; int iB = tB ? gi[3] : gi[2];
            bool tC = vB > vA;       float vC = tC ? vB : vA;       int iC = tC ? iB : iA;
            bool tD = gv[4] > vC;    float bv = tD ? gv[4] : vC;    int bi = tD ? gi[4] : iC;
            int bn = tid + (bi << 9);

            unsigned int ob = __float_as_uint(bv);
            unsigned int ord = (ob & 0x80000000u) ? ~ob : (ob | 0x80000000u);
            unsigned long long key = ((unsigned long long)ord << 32)
                                   | (unsigned int)(~bn);
            // intra-wave 64-lane max -> lane 63
            key = kmax_step<DPP_XOR1 >(key);
            key = kmax_step<DPP_XOR2 >(key);
            key = kmax_step<DPP_HMIRR>(key);
            key = kmax_step<DPP_MIRR >(key);
            key = kmax_step<DPP_BC15 >(key);
            key = kmax_step<DPP_BC31 >(key);
            if (lane == 63) sKy[p][wid] = key;
            __syncthreads();
            // cross-wave: 8 keys, 3 DPP levels -> global max in ALL lanes
            unsigned long long k2 = sKy[p][lane & 7];
            k2 = kmax_step<DPP_XOR1 >(k2);
            k2 = kmax_step<DPP_XOR2 >(k2);
            k2 = kmax_step<DPP_HMIRR>(k2);
            int n = ~((unsigned int)k2);
            lx = sX[n]; ly = sY[n]; lz = sZ[n];   // LDS broadcast
            if (tid == 0) s_sel[it] = n;
        }
        __syncthreads();
        for (int t = tid; t < MP; t += 512) {
            int nc = s_sel[t];
            idxs[b*MP + t] = cib[nc];
            xyz_g[((size_t)b*MP + t)*3 + 0] = sX[nc];
            xyz_g[((size_t)b*MP + t)*3 + 1] = sY[nc];
            xyz_g[((size_t)b*MP + t)*3 + 2] = sZ[nc];
        }
        return;
    }

    // ================= FALLBACK (K > 10240): global reads, LDS dist ========
    {
        float* fD = sXYZ;                 // 30720 floats >= 20480 max K
        for (int c = tid; c < K; c += 512) fD[c] = 1e10f;
        float lx = xcb[0], ly = ycb[0], lz = zcb[0];
        if (tid == 0) s_sel[0] = 0;
        __syncthreads();
        for (int it = 1; it < MP; ++it) {
            const int p = it & 1;
            float bv = -3.4e38f; int bn = 0;
            for (int c = tid; c < K; c += 512) {
                float dx = xcb[c] - lx, dy = ycb[c] - ly, dz = zcb[c] - lz;
                float d = __fadd_rn(__fadd_rn(__fmul_rn(dx,dx), __fmul_rn(dy,dy)),
                                    __fmul_rn(dz,dz));
                float nd = fminf(fD[c], d);
                fD[c] = nd;
                bool w = nd > bv;
                bn = w ? c : bn;
                bv = fmaxf(bv, nd);
            }
            unsigned int ob = __float_as_uint(bv);
            unsigned int ord = (ob & 0x80000000u) ? ~ob : (ob | 0x80000000u);
            unsigned long long key = ((unsigned long long)ord << 32)
                                   | (unsigned int)(~bn);
            key = kmax_step<DPP_XOR1 >(key);
            key = kmax_step<DPP_XOR2 >(key);
            key = kmax_step<DPP_HMIRR>(key);
            key = kmax_step<DPP_MIRR >(key);
            key = kmax_step<DPP_BC15 >(key);
            key = kmax_step<DPP_BC31 >(key);
            if (lane == 63) sKy[p][wid] = key;
            __syncthreads();
            unsigned long long k2 = sKy[p][lane & 7];
            k2 = kmax_step<DPP_XOR1 >(k2);
            k2 = kmax_step<DPP_XOR2 >(k2);
            k2 = kmax_step<DPP_HMIRR>(k2);
            int n = ~((unsigned int)k2);
            lx = xcb[n]; ly = ycb[n]; lz = zcb[n];
            if (tid == 0) s_sel[it] = n;
        }
        __syncthreads();
        for (int t = tid; t < MP; t += 512) {
            int nc = s_sel[t];
            idxs[b*MP + t] = cib[nc];
            xyz_g[((size_t)b*MP + t)*3 + 0] = xcb[nc];
            xyz_g[((size_t)b*MP + t)*3 + 1] = ycb[nc];
            xyz_g[((size_t)b*MP + t)*3 + 2] = zcb[nc];
        }
    }
}

// ---------------------------------------------------------------------------
// K2: gather feat_g[b,m,c] = seed_features[b,c,idx[m]]
// ---------------------------------------------------------------------------
__global__ void k_gather_feat(const float* __restrict__ sf, const int* __restrict__ idxs,
                              float* __restrict__ feat_g)
{
    int bm = blockIdx.x;
    int b = bm >> 10;
    int n = idxs[bm];
    const float* src = sf + (size_t)b*CF*NPTS + n;
    float* dst = feat_g + (size_t)bm*CF;
    for (int c = threadIdx.x; c < CF; c += 256) dst[c] = src[(size_t)c * NPTS];
}

// ---------------------------------------------------------------------------
// K3b: small prep - transpose w2 -> w2t[k][c][o], extract w1 xyz cols
// ---------------------------------------------------------------------------
__global__ void k_prep(const float* __restrict__ w1, const float* __restrict__ w2,
                       float* __restrict__ w2t, float* __restrict__ w1x)
{
    int k = blockIdx.x, cb = blockIdx.y*32, ob = blockIdx.z*32;
    int tx = threadIdx.x & 31, ty = threadIdx.x >> 5;
    __shared__ float t[32][33];
    for (int r = ty; r < 32; r += 8)
        t[r][tx] = w2[((size_t)k*256 + ob + r)*256 + cb + tx];
    __syncthreads();
    for (int r = ty; r < 32; r += 8)
        w2t[((size_t)k*256 + cb + r)*256 + ob + tx] = t[tx][r];
    if (blockIdx.y == 0 && blockIdx.z == 0) {
        int o = threadIdx.x;
        for (int d = 0; d < 3; ++d)
            w1x[(k*3 + d)*256 + o] = w1[((size_t)k*256 + o)*515 + d];
    }
}

// ---------------------------------------------------------------------------
// K3: F1[k][b*1024+n][o] = feat_g[b,n,:] . w1[k][o][3:] + b1[k][o]
// ---------------------------------------------------------------------------
__global__ __launch_bounds__(256)
void k_f1(const float* __restrict__ feat_g, const float* __restrict__ w1,
          const float* __restrict__ b1, float* __restrict__ F1)
{
    const int rt = blockIdx.x * 64;
    const int ot = blockIdx.y * 64;
    const int k  = blockIdx.z;
    const int tid = threadIdx.x;
    __shared__ float As[16][68];
    __shared__ float Bs[16][68];
    const int lr = tid >> 2;
    const int lc = (tid & 3) * 4;
    const int tr = (tid & 15) * 4;
    const int tc = (tid >> 4) * 4;
    float acc[4][4] = {};
    for (int kk = 0; kk < CF; kk += 16) {
        const float* ap = feat_g + (size_t)(rt + lr)*CF + kk + lc;
        As[lc+0][lr] = ap[0]; As[lc+1][lr] = ap[1];
        As[lc+2][lr] = ap[2]; As[lc+3][lr] = ap[3];
        const float* bp = w1 + (size_t)(k*256 + ot + lr)*515 + 3 + kk + lc;
        Bs[lc+0][lr] = bp[0]; Bs[lc+1][lr] = bp[1];
        Bs[lc+2][lr] = bp[2]; Bs[lc+3][lr] = bp[3];
        __syncthreads();
#pragma unroll
        for (int cc = 0; cc < 16; ++cc) {
            float a0=As[cc][tr+0], a1=As[cc][tr+1], a2=As[cc][tr+2], a3=As[cc][tr+3];
            float q0=Bs[cc][tc+0], q1=Bs[cc][tc+1], q2=Bs[cc][tc+2], q3=Bs[cc][tc+3];
            acc[0][0]+=a0*q0; acc[0][1]+=a0*q1; acc[0][2]+=a0*q2; acc[0][3]+=a0*q3;
            acc[1][0]+=a1*q0; acc[1][1]+=a1*q1; acc[1][2]+=a1*q2; acc[1][3]+=a1*q3;
            acc[2][0]+=a2*q0; acc[2][1]+=a2*q1; acc[2][2]+=a2*q2; acc[2][3]+=a2*q3;
            acc[3][0]+=a3*q0; acc[3][1]+=a3*q1; acc[3][2]+=a3*q2; acc[3][3]+=a3*q3;
        }
        __syncthreads();
    }
#pragma unroll
    for (int i = 0; i < 4; ++i)
#pragma unroll
        for (int j = 0; j < 4; ++j)
            F1[((size_t)k*4096 + rt+tr+i)*256 + ot+tc+j] = acc[i][j] + b1[k*256 + ot+tc+j];
}

// ---------------------------------------------------------------------------
// K4: cylinder neighbor query, one block per (b,m), thread = candidate n
// ---------------------------------------------------------------------------
__global__ __launch_bounds__(1024)
void k_nbr(const float* __restrict__ xyz_g, const float* __restrict__ rot,
           int* __restrict__ sel, float* __restrict__ lxyz, int* __restrict__ cnt)
{
    const int bm = blockIdx.x;
    const int b = bm >> 10;
    const int tid = threadIdx.x;
    const int lane = tid & 63, wid = tid >> 6;
    __shared__ float sR[9], sC[3];
    __shared__ int   sSel[4][16];
    __shared__ float sL[4][16][3];
    __shared__ int   sW[16];
    __shared__ int   sCnt[4];
    __shared__ float sFb[3];
    if (tid < 9) sR[tid] = rot[(size_t)bm*9 + tid];
    if (tid < 3) sC[tid] = xyz_g[(size_t)bm*3 + tid];
    __syncthreads();
    float x = xyz_g[((size_t)b*MP + tid)*3 + 0];
    float y = xyz_g[((size_t)b*MP + tid)*3 + 1];
    float z = xyz_g[((size_t)b*MP + tid)*3 + 2];
    float dx = x - sC[0], dy = y - sC[1], dz = z - sC[2];
    float l0 = __fadd_rn(__fadd_rn(__fmul_rn(dx,sR[0]), __fmul_rn(dy,sR[3])), __fmul_rn(dz,sR[6]));
    float l1 = __fadd_rn(__fadd_rn(__fmul_rn(dx,sR[1]), __fmul_rn(dy,sR[4])), __fmul_rn(dz,sR[7]));
    float l2 = __fadd_rn(__fadd_rn(__fmul_rn(dx,sR[2]), __fmul_rn(dy,sR[5])), __fmul_rn(dz,sR[8]));
    float r2 = __fadd_rn(__fmul_rn(l1,l1), __fmul_rn(l2,l2));
    bool basec = (l0 > -0.02f) && (l0 < 0.04f);
    if (tid == 0) { sFb[0]=l0; sFb[1]=l1; sFb[2]=l2; }
    for (int k = 0; k < 4; ++k) {
        bool c = basec && (r2 < c_r2[k]);
        unsigned long long bal = __ballot(c);
        if (lane == 0) sW[wid] = __popcll(bal);
        __syncthreads();
        int pre = 0, tot = 0;
        for (int w = 0; w < 16; ++w) { int cw = sW[w]; tot += cw; if (w < wid) pre += cw; }
        int rank = pre + __popcll(bal & ((1ull << lane) - 1ull));
        if (c && rank < 16) {
            sSel[k][rank] = tid;
            sL[k][rank][0] = l0; sL[k][rank][1] = l1; sL[k][rank][2] = l2;
        }
        if (tid == 0) sCnt[k] = min(tot, 16);
        __syncthreads();
    }
    if (tid < 64) {
        int k = tid >> 4, j = tid & 15;
        int ck = sCnt[k];
        int src = (j < ck) ? j : 0;
        int v; float a0, a1, a2;
        if (ck > 0) { v = sSel[k][src]; a0=sL[k][src][0]; a1=sL[k][src][1]; a2=sL[k][src][2]; }
        else        { v = 0; a0=sFb[0]; a1=sFb[1]; a2=sFb[2]; }
        size_t off = ((size_t)bm*4 + k)*16 + j;
        sel[off] = v;
        lxyz[off*3+0]=a0; lxyz[off*3+1]=a1; lxyz[off*3+2]=a2;
        if (j == 0) cnt[bm*4 + k] = (ck > 0) ? ck : 1;
    }
}

// ---------------------------------------------------------------------------
// K5: per-task MLP (layer1 via F1 gather + xyz part, layer2 + relu + max)
// ---------------------------------------------------------------------------
__global__ __launch_bounds__(256)
void k_mlp(const float* __restrict__ F1, const float* __restrict__ w1x,
           const float* __restrict__ w2t, const float* __restrict__ b2,
           const int* __restrict__ sel, const float* __restrict__ lxyz,
           const int* __restrict__ cnt, float* __restrict__ cat)
{
    const int gid = blockIdx.x;       // 1024 groups * 4 k
    const int k = gid & 3;
    const int g0 = (gid >> 2) * 4;    // bm base (groups never straddle a batch)
    const int o = threadIdx.x;
    __shared__ float h1s[64][256];    // 64 KB
    int u0 = cnt[(g0+0)*4 + k], u1 = cnt[(g0+1)*4 + k],
        u2 = cnt[(g0+2)*4 + k], u3 = cnt[(g0+3)*4 + k];
    int off1 = u0, off2 = u0+u1, off3 = off2+u2, tot = off3+u3;
    const float wx0 = w1x[(k*3+0)*256 + o];
    const float wx1 = w1x[(k*3+1)*256 + o];
    const float wx2 = w1x[(k*3+2)*256 + o];
    const float rad = c_rad[k];
    const int bbase = (g0 >> 10) * MP;
    for (int r = 0; r < tot; ++r) {
        int t = (r >= off1) + (r >= off2) + (r >= off3);
        int toff = (t==0) ? 0 : ((t==1) ? off1 : ((t==2) ? off2 : off3));
        int j = r - toff;
        int bmk = (g0 + t)*4 + k;
        int n = sel[(size_t)bmk*16 + j];
        float lx = lxyz[((size_t)bmk*16 + j)*3 + 0];
        float ly = lxyz[((size_t)bmk*16 + j)*3 + 1];
        float lz = lxyz[((size_t)bmk*16 + j)*3 + 2];
        float v = F1[((size_t)k*4096 + bbase + n)*256 + o];
        v += (lx/rad)*wx0 + (ly/rad)*wx1 + (lz/rad)*wx2;
        h1s[r][o] = fmaxf(v, 0.f);
    }
    __syncthreads();
    const float b2v = b2[k*256 + o];
    float m0=0.f, m1=0.f, m2=0.f, m3=0.f;
    const float* w2c = w2t + (size_t)k*65536 + o;
    for (int base = 0; base < tot; base += 4) {
        int r0 = base;
        int r1 = min(base+1, tot-1);
        int r2 = min(base+2, tot-1);
        int r3 = min(base+3, tot-1);
        float a0=0.f, a1=0.f, a2=0.f, a3=0.f;
        for (int c = 0; c < 256; c += 4) {
            float wA = w2c[(c+0)*256], wB = w2c[(c+1)*256];
            float wC = w2c[(c+2)*256], wD = w2c[(c+3)*256];
            float4 h;
            h = *(const float4*)&h1s[r0][c]; a0 += h.x*wA + h.y*wB + h.z*wC + h.w*wD;
            h = *(const float4*)&h1s[r1][c]; a1 += h.x*wA + h.y*wB + h.z*wC + h.w*wD;
            h = *(const float4*)&h1s[r2][c]; a2 += h.x*wA + h.y*wB + h.z*wC + h.w*wD;
            h = *(const float4*)&h1s[r3][c]; a3 += h.x*wA + h.y*wB + h.z*wC + h.w*wD;
        }
#pragma unroll
        for (int q = 0; q < 4; ++q) {
            int r = base + q;
            if (r < tot) {
                float a = (q==0) ? a0 : ((q==1) ? a1 : ((q==2) ? a2 : a3));
                int t = (r >= off1) + (r >= off2) + (r >= off3);
                float val = fmaxf(a + b2v, 0.f);
                if      (t==0) m0 = fmaxf(m0, val);
                else if (t==1) m1 = fmaxf(m1, val);
                else if (t==2) m2 = fmaxf(m2, val);
                else           m3 = fmaxf(m3, val);
            }
        }
    }
    cat[(size_t)(g0+0)*1024 + k*256 + o] = m0;
    cat[(size_t)(g0+1)*1024 + k*256 + o] = m1;
    cat[(size_t)(g0+2)*1024 + k*256 + o] = m2;
    cat[(size_t)(g0+3)*1024 + k*256 + o] = m3;
}

// ---------------------------------------------------------------------------
// K6: transpose cat[b][m][f] -> catT[b][f][m]
// ---------------------------------------------------------------------------
__global__ void k_transpose(const float* __restrict__ cat, float* __restrict__ catT)
{
    int bt = blockIdx.x;
    int b = bt >> 10;
    int t2 = bt & 1023;
    int mi = (t2 >> 5) * 32, fi = (t2 & 31) * 32;
    int tx = threadIdx.x & 31, ty = threadIdx.x >> 5;
    __shared__ float t[32][33];
    const float* src = cat + (size_t)b * 1048576;
    float* dst = catT + (size_t)b * 1048576;
    for (int r = ty; r < 32; r += 8) t[r][tx] = src[(size_t)(mi + r)*1024 + fi + tx];
    __syncthreads();
    for (int r = ty; r < 32; r += 8) dst[(size_t)(fi + r)*1024 + mi + tx] = t[tx][r];
}

// ---------------------------------------------------------------------------
// K7: fused[b][o][m] = sum_f cat[b][m][f]*fuse_w[o][f] + fuse_b[o]
// ---------------------------------------------------------------------------
__global__ __launch_bounds__(256)
void k_fuse(const float* __restrict__ catT, const float* __restrict__ fw,
            const float* __restrict__ fb, float* __restrict__ out)
{
    const int o0 = blockIdx.x * 4;
    const int b = blockIdx.y;
    const int m = threadIdx.x * 4;
    const float* ct = catT + (size_t)b * 1048576 + m;
    float4 a0 = {0,0,0,0}, a1 = a0, a2 = a0, a3 = a0;
    for (int f = 0; f < 1024; ++f) {
        const float4 cv = *(const float4*)(ct + (size_t)f*1024);
        float w0 = fw[(size_t)(o0+0)*1024 + f];
        float w1 = fw[(size_t)(o0+1)*1024 + f];
        float w2 = fw[(size_t)(o0+2)*1024 + f];
        float w3 = fw[(size_t)(o0+3)*1024 + f];
        a0.x += cv.x*w0; a0.y += cv.y*w0; a0.z += cv.z*w0; a0.w += cv.w*w0;
        a1.x += cv.x*w1; a1.y += cv.y*w1; a1.z += cv.z*w1; a1.w += cv.w*w1;
        a2.x += cv.x*w2; a2.y += cv.y*w2; a2.z += cv.z*w2; a2.w += cv.w*w2;
        a3.x += cv.x*w3; a3.y += cv.y*w3; a3.z += cv.z*w3; a3.w += cv.w*w3;
    }
#pragma unroll
    for (int q = 0; q < 4; ++q) {
        float bb = fb[o0+q];
        float4 r = (q==0) ? a0 : ((q==1) ? a1 : ((q==2) ? a2 : a3));
        r.x += bb; r.y += bb; r.z += bb; r.w += bb;
        *(float4*)&out[((size_t)b*256 + o0 + q)*1024 + m] = r;
    }
}

// ---------------------------------------------------------------------------
extern "C" void kernel_launch(void* const* d_in, const int* in_sizes, int n_in,
                              void* d_out, int out_size, void* d_ws, size_t ws_size,
                              hipStream_t stream)
{
    const float* seed_xyz      = (const float*)d_in[0];
    const float* seed_features = (const float*)d_in[1];
    const float* objectness    = (const float*)d_in[2];
    const float* graspness     = (const float*)d_in[3];
    const float* rot           = (const float*)d_in[4];
    const float* w1            = (const float*)d_in[5];
    const float* b1            = (const float*)d_in[6];
    const float* w2            = (const float*)d_in[7];
    const float* b2            = (const float*)d_in[8];
    const float* fw            = (const float*)d_in[9];
    const float* fb            = (const float*)d_in[10];
    float* out = (float*)d_out;

    char* ws = (char*)d_ws;
    size_t off = 0;
    int*   idxs   = (int*)(ws + off);  off += 16u<<10;            // 16 KB
    float* xyz_g  = (float*)(ws + off); off += 48u<<10;           // 48 KB
    float* feat_g = (float*)(ws + off); off += 8u<<20;            // 8 MB
    float* F1     = (float*)(ws + off); off += 16u<<20;           // 16 MB
    float* w2t    = (float*)(ws + off); off += 1u<<20;            // 1 MB
    float* w1x    = (float*)(ws + off); off += 64u<<10;           // 12 KB used
    int*   sel    = (int*)(ws + off);   off += 1u<<20;            // 1 MB
    int*   cnt    = (int*)(ws + off);   off += 64u<<10;           // 64 KB
    float* lxyz   = (float*)(ws + off); off += 3u<<20;            // 3 MB
    float* cat    = (float*)(ws + off); off += 16u<<20;           // 16 MB
    float* catT   = (float*)(ws + off); off += 16u<<20;           // 16 MB

    // FPS compaction scratch aliases `cat` (first written much later by k_mlp)
    float* xc = cat;
    float* yc = cat + 4*20480;
    float* zc = cat + 8*20480;
    int*   ci = (int*)(cat + 12*20480);
    // K values live in the unused tail of the w1x region (k_prep writes 12 KB)
    int*   kv = (int*)((char*)w1x + 32768);

    k_fps_compact<<<NB, 1024, 0, stream>>>(seed_xyz, objectness, graspness,
                                           xc, yc, zc, ci, kv);
    k_fps_loop<<<NB, 512, 0, stream>>>(seed_xyz, kv, xc, yc, zc, ci, idxs, xyz_g);
    k_prep<<<dim3(4,8,8), 256, 0, stream>>>(w1, w2, w2t, w1x);
    k_gather_feat<<<NB*MP, 256, 0, stream>>>(seed_features, idxs, feat_g);
    k_f1<<<dim3(64,4,4), 256, 0, stream>>>(feat_g, w1, b1, F1);
    k_nbr<<<NB*MP, 1024, 0, stream>>>(xyz_g, rot, sel, lxyz, cnt);
    k_mlp<<<4096, 256, 0, stream>>>(F1, w1x, w2t, b2, sel, lxyz, cnt, cat);
    k_transpose<<<4096, 256, 0, stream>>>(cat, catT);
    k_fuse<<<dim3(64,4), 256, 0, stream>>>(catT, fw, fb, out);
}

// Round 4
// 1704.318 us; speedup vs baseline: 1.2010x; 1.0124x over previous
//
#include <hip/hip_runtime.h>
#include <cstdint>
#include <cfloat>
#include <climits>

#define NPTS 20000
#define NB 4
#define MP 1024
#define CF 512
#define MAXCH 20         // compaction chunks (20*1024 >= 20000)
#define KFAST 10240      // fast path covers K <= 10240 (K~9000 expected)
#define PPT 20           // points per thread in loop kernel: 512*20 = 10240

__constant__ float c_r2[4]  = { (float)(0.025*0.025), (float)(0.05*0.05),
                                (float)(0.075*0.075), (float)(0.1*0.1) };
__constant__ float c_rad[4] = { 0.025f, 0.05f, 0.075f, 0.1f };

// DPP ctrl codes (gfx9/CDNA encoding)
#define DPP_XOR1   0xB1   // quad_perm {1,0,3,2}
#define DPP_XOR2   0x4E   // quad_perm {2,3,0,1}
#define DPP_HMIRR  0x141  // row_half_mirror = xor7 within 8
#define DPP_MIRR   0x140  // row_mirror = xor15 within 16
#define DPP_BC15   0x142  // broadcast lane15 of each row to next row
#define DPP_BC31   0x143  // broadcast lane31 to lanes 32..63

// One DPP butterfly/broadcast step of a 64-bit max-reduce, entirely on VALU.
// bound_ctrl=false + old=src: lanes with no valid source keep their value,
// which is harmless under max.
template<int CTRL>
__device__ __forceinline__ unsigned long long kmax_step(unsigned long long k)
{
    unsigned int lo = (unsigned int)k;
    unsigned int hi = (unsigned int)(k >> 32);
    unsigned int olo = (unsigned int)__builtin_amdgcn_update_dpp((int)lo, (int)lo, CTRL, 0xf, 0xf, false);
    unsigned int ohi = (unsigned int)__builtin_amdgcn_update_dpp((int)hi, (int)hi, CTRL, 0xf, 0xf, false);
    unsigned long long ok = ((unsigned long long)ohi << 32) | (unsigned long long)olo;
    return (ok > k) ? ok : k;
}

// ---------------------------------------------------------------------------
// K1a: order-preserving compaction of masked points, one block per batch.
// Writes compacted x|y|z|orig-index arrays + K to global.
// ---------------------------------------------------------------------------
__global__ __launch_bounds__(1024)
void k_fps_compact(const float* __restrict__ xyz, const float* __restrict__ obj,
                   const float* __restrict__ grasp,
                   float* __restrict__ xc, float* __restrict__ yc,
                   float* __restrict__ zc, int* __restrict__ ci,
                   int* __restrict__ kv)
{
    const int b = blockIdx.x;
    const int tid = threadIdx.x;
    const int lane = tid & 63, wid = tid >> 6;
    const float* xb  = xyz   + (size_t)b * NPTS * 3;
    const float* ob0 = obj   + (size_t)b * 2 * NPTS;
    const float* ob1 = ob0 + NPTS;
    const float* gb  = grasp + (size_t)b * NPTS;
    float* xcb = xc + (size_t)b * 20480;
    float* ycb = yc + (size_t)b * 20480;
    float* zcb = zc + (size_t)b * 20480;
    int*   cib = ci + (size_t)b * 20480;

    __shared__ int sWaveCnt[16];

    int kbase = 0;
    for (int i = 0; i < MAXCH; ++i) {
        int n = i * MP + tid;
        bool msk = false; float x = 0.f, y = 0.f, z = 0.f;
        if (n < NPTS) {
            msk = (ob1[n] > ob0[n]) && (gb[n] > 0.1f);
            if (msk) { x = xb[n*3+0]; y = xb[n*3+1]; z = xb[n*3+2]; }
        }
        unsigned long long bal = __ballot(msk);
        if (lane == 0) sWaveCnt[wid] = __popcll(bal);
        __syncthreads();
        int pre = 0, tot = 0;
        for (int w = 0; w < 16; ++w) { int c = sWaveCnt[w]; tot += c; if (w < wid) pre += c; }
        if (msk) {
            int rank = kbase + pre + __popcll(bal & ((1ull << lane) - 1ull));
            xcb[rank] = x; ycb[rank] = y; zcb[rank] = z; cib[rank] = n;
        }
        kbase += tot;
        __syncthreads();
    }
    if (tid == 0) kv[b] = kbase;
}

// ---------------------------------------------------------------------------
// K1b: the serial FPS loop. 512 threads (8 waves), ALL working.
// launch_bounds(512,2) -> 256-VGPR cap. Round-3 lesson: the compiler
// REMATERIALIZED px/py/pz from LDS every iteration (VGPR_Count=88, not
// ~150) -> 123 KB/iter of LDS re-reads saturated the LDS pipe. Fix: pin
// each element with an empty asm "+v" after init -- the value becomes
// opaque, so it must stay live in a VGPR. Argmax per thread is a 5-level
// cmp/cndmask TREE; cross-lane is a pure-VALU DPP butterfly. Exact
// numerics: rn ops, no contraction, first-max / min-index tie-break.
// ---------------------------------------------------------------------------
__global__ __launch_bounds__(512, 2)
void k_fps_loop(const float* __restrict__ xyz, const int* __restrict__ kv,
                const float* __restrict__ xc, const float* __restrict__ yc,
                const float* __restrict__ zc, const int* __restrict__ ci,
                int* __restrict__ idxs, float* __restrict__ xyz_g)
{
    const int b = blockIdx.x;
    const int tid = threadIdx.x;
    const int lane = tid & 63, wid = tid >> 6;   // 8 waves
    const float* xb  = xyz + (size_t)b * NPTS * 3;
    const float* xcb = xc + (size_t)b * 20480;
    const float* ycb = yc + (size_t)b * 20480;
    const float* zcb = zc + (size_t)b * 20480;
    const int*   cib = ci + (size_t)b * 20480;

    __shared__ float sXYZ[3 * KFAST];          // 120 KB: x | y | z mirrors
    __shared__ int   s_sel[MP];                // 4 KB
    __shared__ unsigned long long sKy[2][8];
    float* sX = sXYZ;
    float* sY = sXYZ + KFAST;
    float* sZ = sXYZ + 2 * KFAST;

    const int K = kv[b];

    if (K == 0) {                        // ref: argmax of all-equal -> 0 forever
        for (int t = tid; t < MP; t += 512) {
            idxs[b*MP + t] = 0;
            xyz_g[((size_t)b*MP + t)*3 + 0] = xb[0];
            xyz_g[((size_t)b*MP + t)*3 + 1] = xb[1];
            xyz_g[((size_t)b*MP + t)*3 + 2] = xb[2];
        }
        return;
    }

    if (K <= KFAST) {
        // ---- stage compacted coords into LDS (zero-padded to KFAST) ----
        for (int c = tid; c < KFAST; c += 512) {
            bool v = c < K;
            sX[c] = v ? xcb[c] : 0.f;
            sY[c] = v ? ycb[c] : 0.f;
            sZ[c] = v ? zcb[c] : 0.f;
        }
        __syncthreads();

        float px[PPT], py[PPT], pz[PPT], pd[PPT];
#pragma unroll
        for (int i = 0; i < PPT; ++i) {
            int c = tid + (i << 9);              // c = tid + i*512
            px[i] = sX[c]; py[i] = sY[c]; pz[i] = sZ[c];
            pd[i] = (c < K) ? 1e10f : -3.0e38f;
            // PIN in VGPRs: "+v" makes the value opaque so the compiler
            // cannot rematerialize it from LDS inside the loop (round-3 bug).
            asm volatile("" : "+v"(px[i]), "+v"(py[i]), "+v"(pz[i]));
        }
        float lx = sX[0], ly = sY[0], lz = sZ[0];
        if (tid == 0) s_sel[0] = 0;

        for (int it = 1; it < MP; ++it) {
            const int p = it & 1;
            // ---- distance update (independent across the 20 points) ----
#pragma unroll
            for (int i = 0; i < PPT; ++i) {
                float dx = px[i] - lx, dy = py[i] - ly, dz = pz[i] - lz;
                float d = __fadd_rn(__fadd_rn(__fmul_rn(dx,dx), __fmul_rn(dy,dy)),
                                    __fmul_rn(dz,dz));
                pd[i] = fminf(pd[i], d);
            }
            // ---- per-thread argmax: tree, depth 5 (tie -> smaller i) ----
            float gv[5]; int gi[5];
#pragma unroll
            for (int g = 0; g < 5; ++g) {
                const int i0 = g * 4;
                bool t0 = pd[i0+1] > pd[i0+0];
                float v01 = t0 ? pd[i0+1] : pd[i0+0];
                int   i01 = t0 ? (i0+1) : (i0+0);
                bool t1 = pd[i0+3] > pd[i0+2];
                float v23 = t1 ? pd[i0+3] : pd[i0+2];
                int   i23 = t1 ? (i0+3) : (i0+2);
                bool t2 = v23 > v01;
                gv[g] = t2 ? v23 : v01;
                gi[g] = t2 ? i23 : i01;
            }
            bool tA = gv[1] > gv[0]; float vA = tA ? gv[1] : gv[0]; int iA = tA ? gi[1] : gi[0];
            bool tB = gv[3] > gv[2]; float vB = tB ? gv[3] : gv[2]; int iB = tB ? gi[3] : gi[2];
            bool tC = vB > vA;       float vC = tC ? vB : vA;       int iC = tC ? iB : iA;
            bool tD = gv[4] > vC;    float bv = tD ? gv[4] : vC;    int bi = tD ? gi[4] : iC;
            int bn = tid + (bi << 9);

            unsigned int ob = __float_as_uint(bv);
            unsigned int ord = (ob & 0x80000000u) ? ~ob : (ob | 0x80000000u);
            unsigned long long key = ((unsigned long long)ord << 32)
                                   | (unsigned int)(~bn);
            // intra-wave 64-lane max -> lane 63
            key = kmax_step<DPP_XOR1 >(key);
            key = kmax_step<DPP_XOR2 >(key);
            key = kmax_step<DPP_HMIRR>(key);
            key = kmax_step<DPP_MIRR >(key);
            key = kmax_step<DPP_BC15 >(key);
            key = kmax_step<DPP_BC31 >(key);
            if (lane == 63) sKy[p][wid] = key;
            __syncthreads();
            // cross-wave: 8 keys, 3 DPP levels -> global max in ALL lanes
            unsigned long long k2 = sKy[p][lane & 7];
            k2 = kmax_step<DPP_XOR1 >(k2);
            k2 = kmax_step<DPP_XOR2 >(k2);
            k2 = kmax_step<DPP_HMIRR>(k2);
            int n = ~((unsigned int)k2);
            lx = sX[n]; ly = sY[n]; lz = sZ[n];   // LDS broadcast
            if (tid == 0) s_sel[it] = n;
        }
        __syncthreads();
        for (int t = tid; t < MP; t += 512) {
            int nc = s_sel[t];
            idxs[b*MP + t] = cib[nc];
            xyz_g[((size_t)b*MP + t)*3 + 0] = sX[nc];
            xyz_g[((size_t)b*MP + t)*3 + 1] = sY[nc];
            xyz_g[((size_t)b*MP + t)*3 + 2] = sZ[nc];
        }
        return;
    }

    // ================= FALLBACK (K > 10240): global reads, LDS dist ========
    {
        float* fD = sXYZ;                 // 30720 floats >= 20480 max K
        for (int c = tid; c < K; c += 512) fD[c] = 1e10f;
        float lx = xcb[0], ly = ycb[0], lz = zcb[0];
        if (tid == 0) s_sel[0] = 0;
        __syncthreads();
        for (int it = 1; it < MP; ++it) {
            const int p = it & 1;
            float bv = -3.4e38f; int bn = 0;
            for (int c = tid; c < K; c += 512) {
                float dx = xcb[c] - lx, dy = ycb[c] - ly, dz = zcb[c] - lz;
                float d = __fadd_rn(__fadd_rn(__fmul_rn(dx,dx), __fmul_rn(dy,dy)),
                                    __fmul_rn(dz,dz));
                float nd = fminf(fD[c], d);
                fD[c] = nd;
                bool w = nd > bv;
                bn = w ? c : bn;
                bv = fmaxf(bv, nd);
            }
            unsigned int ob = __float_as_uint(bv);
            unsigned int ord = (ob & 0x80000000u) ? ~ob : (ob | 0x80000000u);
            unsigned long long key = ((unsigned long long)ord << 32)
                                   | (unsigned int)(~bn);
            key = kmax_step<DPP_XOR1 >(key);
            key = kmax_step<DPP_XOR2 >(key);
            key = kmax_step<DPP_HMIRR>(key);
            key = kmax_step<DPP_MIRR >(key);
            key = kmax_step<DPP_BC15 >(key);
            key = kmax_step<DPP_BC31 >(key);
            if (lane == 63) sKy[p][wid] = key;
            __syncthreads();
            unsigned long long k2 = sKy[p][lane & 7];
            k2 = kmax_step<DPP_XOR1 >(k2);
            k2 = kmax_step<DPP_XOR2 >(k2);
            k2 = kmax_step<DPP_HMIRR>(k2);
            int n = ~((unsigned int)k2);
            lx = xcb[n]; ly = ycb[n]; lz = zcb[n];
            if (tid == 0) s_sel[it] = n;
        }
        __syncthreads();
        for (int t = tid; t < MP; t += 512) {
            int nc = s_sel[t];
            idxs[b*MP + t] = cib[nc];
            xyz_g[((size_t)b*MP + t)*3 + 0] = xcb[nc];
            xyz_g[((size_t)b*MP + t)*3 + 1] = ycb[nc];
            xyz_g[((size_t)b*MP + t)*3 + 2] = zcb[nc];
        }
    }
}

// ---------------------------------------------------------------------------
// K2: gather feat_g[b,m,c] = seed_features[b,c,idx[m]]
// ---------------------------------------------------------------------------
__global__ void k_gather_feat(const float* __restrict__ sf, const int* __restrict__ idxs,
                              float* __restrict__ feat_g)
{
    int bm = blockIdx.x;
    int b = bm >> 10;
    int n = idxs[bm];
    const float* src = sf + (size_t)b*CF*NPTS + n;
    float* dst = feat_g + (size_t)bm*CF;
    for (int c = threadIdx.x; c < CF; c += 256) dst[c] = src[(size_t)c * NPTS];
}

// ---------------------------------------------------------------------------
// K3b: small prep - transpose w2 -> w2t[k][c][o], extract w1 xyz cols
// ---------------------------------------------------------------------------
__global__ void k_prep(const float* __restrict__ w1, const float* __restrict__ w2,
                       float* __restrict__ w2t, float* __restrict__ w1x)
{
    int k = blockIdx.x, cb = blockIdx.y*32, ob = blockIdx.z*32;
    int tx = threadIdx.x & 31, ty = threadIdx.x >> 5;
    __shared__ float t[32][33];
    for (int r = ty; r < 32; r += 8)
        t[r][tx] = w2[((size_t)k*256 + ob + r)*256 + cb + tx];
    __syncthreads();
    for (int r = ty; r < 32; r += 8)
        w2t[((size_t)k*256 + cb + r)*256 + ob + tx] = t[tx][r];
    if (blockIdx.y == 0 && blockIdx.z == 0) {
        int o = threadIdx.x;
        for (int d = 0; d < 3; ++d)
            w1x[(k*3 + d)*256 + o] = w1[((size_t)k*256 + o)*515 + d];
    }
}

// ---------------------------------------------------------------------------
// K3: F1[k][b*1024+n][o] = feat_g[b,n,:] . w1[k][o][3:] + b1[k][o]
// ---------------------------------------------------------------------------
__global__ __launch_bounds__(256)
void k_f1(const float* __restrict__ feat_g, const float* __restrict__ w1,
          const float* __restrict__ b1, float* __restrict__ F1)
{
    const int rt = blockIdx.x * 64;
    const int ot = blockIdx.y * 64;
    const int k  = blockIdx.z;
    const int tid = threadIdx.x;
    __shared__ float As[16][68];
    __shared__ float Bs[16][68];
    const int lr = tid >> 2;
    const int lc = (tid & 3) * 4;
    const int tr = (tid & 15) * 4;
    const int tc = (tid >> 4) * 4;
    float acc[4][4] = {};
    for (int kk = 0; kk < CF; kk += 16) {
        const float* ap = feat_g + (size_t)(rt + lr)*CF + kk + lc;
        As[lc+0][lr] = ap[0]; As[lc+1][lr] = ap[1];
        As[lc+2][lr] = ap[2]; As[lc+3][lr] = ap[3];
        const float* bp = w1 + (size_t)(k*256 + ot + lr)*515 + 3 + kk + lc;
        Bs[lc+0][lr] = bp[0]; Bs[lc+1][lr] = bp[1];
        Bs[lc+2][lr] = bp[2]; Bs[lc+3][lr] = bp[3];
        __syncthreads();
#pragma unroll
        for (int cc = 0; cc < 16; ++cc) {
            float a0=As[cc][tr+0], a1=As[cc][tr+1], a2=As[cc][tr+2], a3=As[cc][tr+3];
            float q0=Bs[cc][tc+0], q1=Bs[cc][tc+1], q2=Bs[cc][tc+2], q3=Bs[cc][tc+3];
            acc[0][0]+=a0*q0; acc[0][1]+=a0*q1; acc[0][2]+=a0*q2; acc[0][3]+=a0*q3;
            acc[1][0]+=a1*q0; acc[1][1]+=a1*q1; acc[1][2]+=a1*q2; acc[1][3]+=a1*q3;
            acc[2][0]+=a2*q0; acc[2][1]+=a2*q1; acc[2][2]+=a2*q2; acc[2][3]+=a2*q3;
            acc[3][0]+=a3*q0; acc[3][1]+=a3*q1; acc[3][2]+=a3*q2; acc[3][3]+=a3*q3;
        }
        __syncthreads();
    }
#pragma unroll
    for (int i = 0; i < 4; ++i)
#pragma unroll
        for (int j = 0; j < 4; ++j)
            F1[((size_t)k*4096 + rt+tr+i)*256 + ot+tc+j] = acc[i][j] + b1[k*256 + ot+tc+j];
}

// ---------------------------------------------------------------------------
// K4: cylinder neighbor query, one block per (b,m), thread = candidate n
// ---------------------------------------------------------------------------
__global__ __launch_bounds__(1024)
void k_nbr(const float* __restrict__ xyz_g, const float* __restrict__ rot,
           int* __restrict__ sel, float* __restrict__ lxyz, int* __restrict__ cnt)
{
    const int bm = blockIdx.x;
    const int b = bm >> 10;
    const int tid = threadIdx.x;
    const int lane = tid & 63, wid = tid >> 6;
    __shared__ float sR[9], sC[3];
    __shared__ int   sSel[4][16];
    __shared__ float sL[4][16][3];
    __shared__ int   sW[16];
    __shared__ int   sCnt[4];
    __shared__ float sFb[3];
    if (tid < 9) sR[tid] = rot[(size_t)bm*9 + tid];
    if (tid < 3) sC[tid] = xyz_g[(size_t)bm*3 + tid];
    __syncthreads();
    float x = xyz_g[((size_t)b*MP + tid)*3 + 0];
    float y = xyz_g[((size_t)b*MP + tid)*3 + 1];
    float z = xyz_g[((size_t)b*MP + tid)*3 + 2];
    float dx = x - sC[0], dy = y - sC[1], dz = z - sC[2];
    float l0 = __fadd_rn(__fadd_rn(__fmul_rn(dx,sR[0]), __fmul_rn(dy,sR[3])), __fmul_rn(dz,sR[6]));
    float l1 = __fadd_rn(__fadd_rn(__fmul_rn(dx,sR[1]), __fmul_rn(dy,sR[4])), __fmul_rn(dz,sR[7]));
    float l2 = __fadd_rn(__fadd_rn(__fmul_rn(dx,sR[2]), __fmul_rn(dy,sR[5])), __fmul_rn(dz,sR[8]));
    float r2 = __fadd_rn(__fmul_rn(l1,l1), __fmul_rn(l2,l2));
    bool basec = (l0 > -0.02f) && (l0 < 0.04f);
    if (tid == 0) { sFb[0]=l0; sFb[1]=l1; sFb[2]=l2; }
    for (int k = 0; k < 4; ++k) {
        bool c = basec && (r2 < c_r2[k]);
        unsigned long long bal = __ballot(c);
        if (lane == 0) sW[wid] = __popcll(bal);
        __syncthreads();
        int pre = 0, tot = 0;
        for (int w = 0; w < 16; ++w) { int cw = sW[w]; tot += cw; if (w < wid) pre += cw; }
        int rank = pre + __popcll(bal & ((1ull << lane) - 1ull));
        if (c && rank < 16) {
            sSel[k][rank] = tid;
            sL[k][rank][0] = l0; sL[k][rank][1] = l1; sL[k][rank][2] = l2;
        }
        if (tid == 0) sCnt[k] = min(tot, 16);
        __syncthreads();
    }
    if (tid < 64) {
        int k = tid >> 4, j = tid & 15;
        int ck = sCnt[k];
        int src = (j < ck) ? j : 0;
        int v; float a0, a1, a2;
        if (ck > 0) { v = sSel[k][src]; a0=sL[k][src][0]; a1=sL[k][src][1]; a2=sL[k][src][2]; }
        else        { v = 0; a0=sFb[0]; a1=sFb[1]; a2=sFb[2]; }
        size_t off = ((size_t)bm*4 + k)*16 + j;
        sel[off] = v;
        lxyz[off*3+0]=a0; lxyz[off*3+1]=a1; lxyz[off*3+2]=a2;
        if (j == 0) cnt[bm*4 + k] = (ck > 0) ? ck : 1;
    }
}

// ---------------------------------------------------------------------------
// K5: per-task MLP (layer1 via F1 gather + xyz part, layer2 + relu + max)
// ---------------------------------------------------------------------------
__global__ __launch_bounds__(256)
void k_mlp(const float* __restrict__ F1, const float* __restrict__ w1x,
           const float* __restrict__ w2t, const float* __restrict__ b2,
           const int* __restrict__ sel, const float* __restrict__ lxyz,
           const int* __restrict__ cnt, float* __restrict__ cat)
{
    const int gid = blockIdx.x;       // 1024 groups * 4 k
    const int k = gid & 3;
    const int g0 = (gid >> 2) * 4;    // bm base (groups never straddle a batch)
    const int o = threadIdx.x;
    __shared__ float h1s[64][256];    // 64 KB
    int u0 = cnt[(g0+0)*4 + k], u1 = cnt[(g0+1)*4 + k],
        u2 = cnt[(g0+2)*4 + k], u3 = cnt[(g0+3)*4 + k];
    int off1 = u0, off2 = u0+u1, off3 = off2+u2, tot = off3+u3;
    const float wx0 = w1x[(k*3+0)*256 + o];
    const float wx1 = w1x[(k*3+1)*256 + o];
    const float wx2 = w1x[(k*3+2)*256 + o];
    const float rad = c_rad[k];
    const int bbase = (g0 >> 10) * MP;
    for (int r = 0; r < tot; ++r) {
        int t = (r >= off1) + (r >= off2) + (r >= off3);
        int toff = (t==0) ? 0 : ((t==1) ? off1 : ((t==2) ? off2 : off3));
        int j = r - toff;
        int bmk = (g0 + t)*4 + k;
        int n = sel[(size_t)bmk*16 + j];
        float lx = lxyz[((size_t)bmk*16 + j)*3 + 0];
        float ly = lxyz[((size_t)bmk*16 + j)*3 + 1];
        float lz = lxyz[((size_t)bmk*16 + j)*3 + 2];
        float v = F1[((size_t)k*4096 + bbase + n)*256 + o];
        v += (lx/rad)*wx0 + (ly/rad)*wx1 + (lz/rad)*wx2;
        h1s[r][o] = fmaxf(v, 0.f);
    }
    __syncthreads();
    const float b2v = b2[k*256 + o];
    float m0=0.f, m1=0.f, m2=0.f, m3=0.f;
    const float* w2c = w2t + (size_t)k*65536 + o;
    for (int base = 0; base < tot; base += 4) {
        int r0 = base;
        int r1 = min(base+1, tot-1);
        int r2 = min(base+2, tot-1);
        int r3 = min(base+3, tot-1);
        float a0=0.f, a1=0.f, a2=0.f, a3=0.f;
        for (int c = 0; c < 256; c += 4) {
            float wA = w2c[(c+0)*256], wB = w2c[(c+1)*256];
            float wC = w2c[(c+2)*256], wD = w2c[(c+3)*256];
            float4 h;
            h = *(const float4*)&h1s[r0][c]; a0 += h.x*wA + h.y*wB + h.z*wC + h.w*wD;
            h = *(const float4*)&h1s[r1][c]; a1 += h.x*wA + h.y*wB + h.z*wC + h.w*wD;
            h = *(const float4*)&h1s[r2][c]; a2 += h.x*wA + h.y*wB + h.z*wC + h.w*wD;
            h = *(const float4*)&h1s[r3][c]; a3 += h.x*wA + h.y*wB + h.z*wC + h.w*wD;
        }
#pragma unroll
        for (int q = 0; q < 4; ++q) {
            int r = base + q;
            if (r < tot) {
                float a = (q==0) ? a0 : ((q==1) ? a1 : ((q==2) ? a2 : a3));
                int t = (r >= off1) + (r >= off2) + (r >= off3);
                float val = fmaxf(a + b2v, 0.f);
                if      (t==0) m0 = fmaxf(m0, val);
                else if (t==1) m1 = fmaxf(m1, val);
                else if (t==2) m2 = fmaxf(m2, val);
                else           m3 = fmaxf(m3, val);
            }
        }
    }
    cat[(size_t)(g0+0)*1024 + k*256 + o] = m0;
    cat[(size_t)(g0+1)*1024 + k*256 + o] = m1;
    cat[(size_t)(g0+2)*1024 + k*256 + o] = m2;
    cat[(size_t)(g0+3)*1024 + k*256 + o] = m3;
}

// ---------------------------------------------------------------------------
// K6: transpose cat[b][m][f] -> catT[b][f][m]
// ---------------------------------------------------------------------------
__global__ void k_transpose(const float* __restrict__ cat, float* __restrict__ catT)
{
    int bt = blockIdx.x;
    int b = bt >> 10;
    int t2 = bt & 1023;
    int mi = (t2 >> 5) * 32, fi = (t2 & 31) * 32;
    int tx = threadIdx.x & 31, ty = threadIdx.x >> 5;
    __shared__ float t[32][33];
    const float* src = cat + (size_t)b * 1048576;
    float* dst = catT + (size_t)b * 1048576;
    for (int r = ty; r < 32; r += 8) t[r][tx] = src[(size_t)(mi + r)*1024 + fi + tx];
    __syncthreads();
    for (int r = ty; r < 32; r += 8) dst[(size_t)(fi + r)*1024 + mi + tx] = t[tx][r];
}

// ---------------------------------------------------------------------------
// K7: fused[b][o][m] = sum_f cat[b][m][f]*fuse_w[o][f] + fuse_b[o]
// ---------------------------------------------------------------------------
__global__ __launch_bounds__(256)
void k_fuse(const float* __restrict__ catT, const float* __restrict__ fw,
            const float* __restrict__ fb, float* __restrict__ out)
{
    const int o0 = blockIdx.x * 4;
    const int b = blockIdx.y;
    const int m = threadIdx.x * 4;
    const float* ct = catT + (size_t)b * 1048576 + m;
    float4 a0 = {0,0,0,0}, a1 = a0, a2 = a0, a3 = a0;
    for (int f = 0; f < 1024; ++f) {
        const float4 cv = *(const float4*)(ct + (size_t)f*1024);
        float w0 = fw[(size_t)(o0+0)*1024 + f];
        float w1 = fw[(size_t)(o0+1)*1024 + f];
        float w2 = fw[(size_t)(o0+2)*1024 + f];
        float w3 = fw[(size_t)(o0+3)*1024 + f];
        a0.x += cv.x*w0; a0.y += cv.y*w0; a0.z += cv.z*w0; a0.w += cv.w*w0;
        a1.x += cv.x*w1; a1.y += cv.y*w1; a1.z += cv.z*w1; a1.w += cv.w*w1;
        a2.x += cv.x*w2; a2.y += cv.y*w2; a2.z += cv.z*w2; a2.w += cv.w*w2;
        a3.x += cv.x*w3; a3.y += cv.y*w3; a3.z += cv.z*w3; a3.w += cv.w*w3;
    }
#pragma unroll
    for (int q = 0; q < 4; ++q) {
        float bb = fb[o0+q];
        float4 r = (q==0) ? a0 : ((q==1) ? a1 : ((q==2) ? a2 : a3));
        r.x += bb; r.y += bb; r.z += bb; r.w += bb;
        *(float4*)&out[((size_t)b*256 + o0 + q)*1024 + m] = r;
    }
}

// ---------------------------------------------------------------------------
extern "C" void kernel_launch(void* const* d_in, const int* in_sizes, int n_in,
                              void* d_out, int out_size, void* d_ws, size_t ws_size,
                              hipStream_t stream)
{
    const float* seed_xyz      = (const float*)d_in[0];
    const float* seed_features = (const float*)d_in[1];
    const float* objectness    = (const float*)d_in[2];
    const float* graspness     = (const float*)d_in[3];
    const float* rot           = (const float*)d_in[4];
    const float* w1            = (const float*)d_in[5];
    const float* b1            = (const float*)d_in[6];
    const float* w2            = (const float*)d_in[7];
    const float* b2            = (const float*)d_in[8];
    const float* fw            = (const float*)d_in[9];
    const float* fb            = (const float*)d_in[10];
    float* out = (float*)d_out;

    char* ws = (char*)d_ws;
    size_t off = 0;
    int*   idxs   = (int*)(ws + off);  off += 16u<<10;            // 16 KB
    float* xyz_g  = (float*)(ws + off); off += 48u<<10;           // 48 KB
    float* feat_g = (float*)(ws + off); off += 8u<<20;            // 8 MB
    float* F1     = (float*)(ws + off); off += 16u<<20;           // 16 MB
    float* w2t    = (float*)(ws + off); off += 1u<<20;            // 1 MB
    float* w1x    = (float*)(ws + off); off += 64u<<10;           // 12 KB used
    int*   sel    = (int*)(ws + off);   off += 1u<<20;            // 1 MB
    int*   cnt    = (int*)(ws + off);   off += 64u<<10;           // 64 KB
    float* lxyz   = (float*)(ws + off); off += 3u<<20;            // 3 MB
    float* cat    = (float*)(ws + off); off += 16u<<20;           // 16 MB
    float* catT   = (float*)(ws + off); off += 16u<<20;           // 16 MB

    // FPS compaction scratch aliases `cat` (first written much later by k_mlp)
    float* xc = cat;
    float* yc = cat + 4*20480;
    float* zc = cat + 8*20480;
    int*   ci = (int*)(cat + 12*20480);
    // K values live in the unused tail of the w1x region (k_prep writes 12 KB)
    int*   kv = (int*)((char*)w1x + 32768);

    k_fps_compact<<<NB, 1024, 0, stream>>>(seed_xyz, objectness, graspness,
                                           xc, yc, zc, ci, kv);
    k_fps_loop<<<NB, 512, 0, stream>>>(seed_xyz, kv, xc, yc, zc, ci, idxs, xyz_g);
    k_prep<<<dim3(4,8,8), 256, 0, stream>>>(w1, w2, w2t, w1x);
    k_gather_feat<<<NB*MP, 256, 0, stream>>>(seed_features, idxs, feat_g);
    k_f1<<<dim3(64,4,4), 256, 0, stream>>>(feat_g, w1, b1, F1);
    k_nbr<<<NB*MP, 1024, 0, stream>>>(xyz_g, rot, sel, lxyz, cnt);
    k_mlp<<<4096, 256, 0, stream>>>(F1, w1x, w2t, b2, sel, lxyz, cnt, cat);
    k_transpose<<<4096, 256, 0, stream>>>(cat, catT);
    k_fuse<<<dim3(64,4), 256, 0, stream>>>(catT, fw, fb, out);
}